// Round 13
// baseline (1163.559 us; speedup 1.0000x reference)
//
#include <hip/hip_runtime.h>

#define NUM_USERS 100000
#define NUM_ITEMS 50000
#define N_NODES   150000   // NUM_USERS + NUM_ITEMS
#define DIM       64
#define NNZ_C     10000000
#define BATCH_C   4096
#define NBINS     1172     // ceil(150000/128); bin = dst >> 7 (128 nodes/bin)
#define NBLK      2048
#define CHUNK     4883     // ceil(NNZ / NBLK); 2048*4883 = 10,000,384

// ======== Phase A: per-block histogram over bins (LDS atomics only) ========

__global__ __launch_bounds__(256) void histA_kernel(const int* __restrict__ dst,
                                                    int* __restrict__ H) {
    __shared__ int hist[NBINS];
    int bid = blockIdx.x, t = threadIdx.x;
    for (int i = t; i < NBINS; i += 256) hist[i] = 0;
    __syncthreads();
    int beg = bid * CHUNK;
    int end = beg + CHUNK; if (end > NNZ_C) end = NNZ_C;
    for (int i = beg + t; i < end; i += 256) atomicAdd(&hist[dst[i] >> 7], 1);
    __syncthreads();
    for (int i = t; i < NBINS; i += 256) H[bid * NBINS + i] = hist[i];
}

// ======== Phase B1: per-bin exclusive scan over blocks (H -> O_rel) ========

__global__ __launch_bounds__(256) void scanB1_kernel(int* __restrict__ H,
                                                     int* __restrict__ bin_cnt) {
    __shared__ int sh[256];
    int b = blockIdx.x;
    int t = threadIdx.x;
    int v[8]; int s = 0;
    #pragma unroll
    for (int j = 0; j < 8; ++j) { v[j] = H[(t * 8 + j) * NBINS + b]; s += v[j]; }
    sh[t] = s;
    __syncthreads();
    for (int off = 1; off < 256; off <<= 1) {
        int x = (t >= off) ? sh[t - off] : 0;
        __syncthreads();
        sh[t] += x;
        __syncthreads();
    }
    int run = sh[t] - s;
    if (t == 255) bin_cnt[b] = sh[255];
    #pragma unroll
    for (int j = 0; j < 8; ++j) { H[(t * 8 + j) * NBINS + b] = run; run += v[j]; }
}

// ======== Phase B2: exclusive scan of bin counts -> bin_start ========

__global__ void scanB2_kernel(const int* __restrict__ bin_cnt,
                              int* __restrict__ bin_start,
                              int* __restrict__ row_ptr) {
    __shared__ int sh[256];
    int t = threadIdx.x;
    int v[5]; int s = 0;
    #pragma unroll
    for (int j = 0; j < 5; ++j) {
        int idx = t * 5 + j;
        v[j] = (idx < NBINS) ? bin_cnt[idx] : 0;
        s += v[j];
    }
    sh[t] = s;
    __syncthreads();
    for (int off = 1; off < 256; off <<= 1) {
        int x = (t >= off) ? sh[t - off] : 0;
        __syncthreads();
        sh[t] += x;
        __syncthreads();
    }
    int run = sh[t] - s;
    #pragma unroll
    for (int j = 0; j < 5; ++j) {
        int idx = t * 5 + j;
        if (idx < NBINS) bin_start[idx] = run;
        run += v[j];
    }
    if (t == 0) { bin_start[NBINS] = NNZ_C; row_ptr[N_NODES] = NNZ_C; }
}

// ======== Phase C: LDS counting-sort by bin, stream to bin-contiguous buf ===

__global__ __launch_bounds__(256) void partC_kernel(const int* __restrict__ src,
                                                    const int* __restrict__ dst,
                                                    const float* __restrict__ val,
                                                    const int* __restrict__ H,   // O_rel
                                                    const int* __restrict__ bin_start,
                                                    int2* __restrict__ binBuf) {
    __shared__ int2  edg[CHUNK];
    __shared__ short ebin[CHUNK];
    __shared__ int   hist[NBINS];
    __shared__ int   lscan[NBINS];
    __shared__ int   sh2[256];
    int bid = blockIdx.x, t = threadIdx.x;
    int beg = bid * CHUNK;
    int end = beg + CHUNK; if (end > NNZ_C) end = NNZ_C;
    int cnt = end - beg;

    for (int i = t; i < NBINS; i += 256) hist[i] = 0;
    __syncthreads();
    for (int i = beg + t; i < end; i += 256) atomicAdd(&hist[dst[i] >> 7], 1);
    __syncthreads();

    int v[5]; int s = 0;
    #pragma unroll
    for (int j = 0; j < 5; ++j) {
        int idx = t * 5 + j;
        v[j] = (idx < NBINS) ? hist[idx] : 0;
        s += v[j];
    }
    sh2[t] = s;
    __syncthreads();
    for (int off = 1; off < 256; off <<= 1) {
        int x = (t >= off) ? sh2[t - off] : 0;
        __syncthreads();
        sh2[t] += x;
        __syncthreads();
    }
    int run = sh2[t] - s;
    #pragma unroll
    for (int j = 0; j < 5; ++j) {
        int idx = t * 5 + j;
        if (idx < NBINS) lscan[idx] = run;
        run += v[j];
    }
    __syncthreads();
    for (int i = t; i < NBINS; i += 256) hist[i] = 0;
    __syncthreads();

    for (int i = beg + t; i < end; i += 256) {
        int d = dst[i];
        int b = d >> 7, ld = d & 127;
        int pos = lscan[b] + atomicAdd(&hist[b], 1);
        edg[pos]  = make_int2(src[i] | (ld << 18), __float_as_int(val[i]));
        ebin[pos] = (short)b;
    }
    __syncthreads();

    for (int i = t; i < cnt; i += 256) {
        int b = ebin[i];
        int addr = bin_start[b] + H[bid * NBINS + b] + (i - lscan[b]);
        binBuf[addr] = edg[i];
    }
}

// ======== Phase D: per-bin CSR finalize (one workgroup per bin) ========

__global__ __launch_bounds__(256) void finD_kernel(const int2* __restrict__ binBuf,
                                                   const int* __restrict__ bin_start,
                                                   int2* __restrict__ packed,
                                                   int* __restrict__ row_ptr) {
    __shared__ int hist[128], lscan[128], cur[128];
    int b = blockIdx.x, t = threadIdx.x;
    int beg = bin_start[b], end = bin_start[b + 1];
    if (t < 128) hist[t] = 0;
    __syncthreads();
    for (int i = beg + t; i < end; i += 256)
        atomicAdd(&hist[(binBuf[i].x >> 18) & 127], 1);
    __syncthreads();
    int sv = (t < 128) ? hist[t] : 0;
    if (t < 128) lscan[t] = sv;
    __syncthreads();
    for (int off = 1; off < 128; off <<= 1) {
        int x = 0;
        if (t < 128 && t >= off) x = lscan[t - off];
        __syncthreads();
        if (t < 128) lscan[t] += x;
        __syncthreads();
    }
    if (t < 128) {
        lscan[t] -= sv;
        cur[t] = 0;
        int node = b * 128 + t;
        if (node < N_NODES) row_ptr[node] = beg + lscan[t];
    }
    __syncthreads();
    for (int i = beg + t; i < end; i += 256) {
        int2 e = binBuf[i];
        int ld = (e.x >> 18) & 127;
        int slot = beg + lscan[ld] + atomicAdd(&cur[ld], 1);
        packed[slot] = make_int2(e.x & 0x3FFFF, e.y);
    }
}

// ======== X = concat(uemb, iemb) ========

__global__ __launch_bounds__(256) void concat_kernel(const float* __restrict__ uemb,
                                                     const float* __restrict__ iemb,
                                                     float4* __restrict__ X4) {
    const int NU4 = NUM_USERS * DIM / 4;
    const int NT4 = N_NODES * DIM / 4;
    int i = blockIdx.x * blockDim.x + threadIdx.x;
    int stride = gridDim.x * blockDim.x;
    const float4* u4 = (const float4*)uemb;
    const float4* i4 = (const float4*)iemb;
    for (; i < NT4; i += stride)
        X4[i] = (i < NU4) ? u4[i] : i4[i - NU4];
}

// ======== SpMM: ILP-restructured full-chunk path ========
// Phase 1: all 32 bpermutes -> s[16], v[16]. Phase 2: issue all 16 float4
// gathers into r[16]. Phase 3: 16 FMA rounds. Statically unrolled (registers,
// not scratch). Forces ~16 gathers in flight per wave (VGPR ~100 expected,
// was 44 with the fused loop -> compiler batched only ~8).

__global__ __launch_bounds__(256) void spmm_kernel(const int2* __restrict__ packed,
                                                   const int* __restrict__ row_ptr,
                                                   const float* __restrict__ xin,
                                                   float* __restrict__ xout) {
    int gtid = blockIdx.x * blockDim.x + threadIdx.x;
    int node = gtid >> 6;
    int lane = threadIdx.x & 63;
    if (node >= N_NODES) return;
    int beg = row_ptr[node];
    int end = row_ptr[node + 1];
    int q  = lane >> 4;
    int d4 = lane & 15;
    const float4* xbase = (const float4*)xin + d4;
    float4 acc = make_float4(0.f, 0.f, 0.f, 0.f);

    for (int base = beg; base < end; base += 64) {
        int n = end - base;
        n = n > 64 ? 64 : n;
        int2 p = make_int2(0, 0);
        if (lane < n) p = packed[base + lane];
        if (n == 64) {
            int s[16]; float v[16];
            #pragma unroll
            for (int t = 0; t < 16; ++t) {
                int srclane = (4 * t + q) << 2;
                s[t] = __builtin_amdgcn_ds_bpermute(srclane, p.x);
                v[t] = __int_as_float(__builtin_amdgcn_ds_bpermute(srclane, p.y));
            }
            float4 r[16];
            #pragma unroll
            for (int t = 0; t < 16; ++t) r[t] = xbase[s[t] * 16];
            #pragma unroll
            for (int t = 0; t < 16; ++t) {
                acc.x = fmaf(v[t], r[t].x, acc.x);
                acc.y = fmaf(v[t], r[t].y, acc.y);
                acc.z = fmaf(v[t], r[t].z, acc.z);
                acc.w = fmaf(v[t], r[t].w, acc.w);
            }
        } else {
            int nq = (n + 3) >> 2;
            #pragma unroll 4
            for (int t = 0; t < nq; ++t) {
                int srclane = (4 * t + q) << 2;
                int s  = __builtin_amdgcn_ds_bpermute(srclane, p.x);
                float v = __int_as_float(__builtin_amdgcn_ds_bpermute(srclane, p.y));
                float4 r = xbase[s * 16];
                acc.x = fmaf(v, r.x, acc.x);
                acc.y = fmaf(v, r.y, acc.y);
                acc.z = fmaf(v, r.z, acc.z);
                acc.w = fmaf(v, r.w, acc.w);
            }
        }
    }
    acc.x += __shfl_xor(acc.x, 16);
    acc.y += __shfl_xor(acc.y, 16);
    acc.z += __shfl_xor(acc.z, 16);
    acc.w += __shfl_xor(acc.w, 16);
    acc.x += __shfl_xor(acc.x, 32);
    acc.y += __shfl_xor(acc.y, 32);
    acc.z += __shfl_xor(acc.z, 32);
    acc.w += __shfl_xor(acc.w, 32);
    if (lane < 16)
        ((float4*)(xout + (size_t)node * DIM))[d4] = acc;
}

__global__ __launch_bounds__(256) void spmm_sel_kernel(const int2* __restrict__ packed,
                                                       const int* __restrict__ row_ptr,
                                                       const int* __restrict__ users,
                                                       const int* __restrict__ items,
                                                       const float* __restrict__ h2,
                                                       float* __restrict__ acc_sel) {
    int gtid = blockIdx.x * blockDim.x + threadIdx.x;
    int slot = gtid >> 6;
    int lane = threadIdx.x & 63;
    if (slot >= 2 * BATCH_C) return;
    int node = (slot < BATCH_C) ? users[slot] : (NUM_USERS + items[slot - BATCH_C]);
    int beg = row_ptr[node];
    int end = row_ptr[node + 1];
    int q  = lane >> 4;
    int d4 = lane & 15;
    const float4* xbase = (const float4*)h2 + d4;
    float4 acc = make_float4(0.f, 0.f, 0.f, 0.f);

    for (int base = beg; base < end; base += 64) {
        int n = end - base;
        n = n > 64 ? 64 : n;
        int2 p = make_int2(0, 0);
        if (lane < n) p = packed[base + lane];
        if (n == 64) {
            int s[16]; float v[16];
            #pragma unroll
            for (int t = 0; t < 16; ++t) {
                int srclane = (4 * t + q) << 2;
                s[t] = __builtin_amdgcn_ds_bpermute(srclane, p.x);
                v[t] = __int_as_float(__builtin_amdgcn_ds_bpermute(srclane, p.y));
            }
            float4 r[16];
            #pragma unroll
            for (int t = 0; t < 16; ++t) r[t] = xbase[s[t] * 16];
            #pragma unroll
            for (int t = 0; t < 16; ++t) {
                acc.x = fmaf(v[t], r[t].x, acc.x);
                acc.y = fmaf(v[t], r[t].y, acc.y);
                acc.z = fmaf(v[t], r[t].z, acc.z);
                acc.w = fmaf(v[t], r[t].w, acc.w);
            }
        } else {
            int nq = (n + 3) >> 2;
            #pragma unroll 4
            for (int t = 0; t < nq; ++t) {
                int srclane = (4 * t + q) << 2;
                int s  = __builtin_amdgcn_ds_bpermute(srclane, p.x);
                float v = __int_as_float(__builtin_amdgcn_ds_bpermute(srclane, p.y));
                float4 r = xbase[s * 16];
                acc.x = fmaf(v, r.x, acc.x);
                acc.y = fmaf(v, r.y, acc.y);
                acc.z = fmaf(v, r.z, acc.z);
                acc.w = fmaf(v, r.w, acc.w);
            }
        }
    }
    acc.x += __shfl_xor(acc.x, 16);
    acc.y += __shfl_xor(acc.y, 16);
    acc.z += __shfl_xor(acc.z, 16);
    acc.w += __shfl_xor(acc.w, 16);
    acc.x += __shfl_xor(acc.x, 32);
    acc.y += __shfl_xor(acc.y, 32);
    acc.z += __shfl_xor(acc.z, 32);
    acc.w += __shfl_xor(acc.w, 32);
    if (lane < 16) {
        float4* dst4 = (float4*)(acc_sel + (size_t)slot * DIM) + d4;
        float4 a = *dst4;
        a.x += acc.x; a.y += acc.y; a.z += acc.z; a.w += acc.w;
        *dst4 = a;
    }
}

// ======== selected-row accumulation + dot ========

__global__ __launch_bounds__(256) void init_sel_kernel(const int* __restrict__ users,
                                                       const int* __restrict__ items,
                                                       const float* __restrict__ X,
                                                       float* __restrict__ acc_sel) {
    int gtid = blockIdx.x * blockDim.x + threadIdx.x;
    int idx = gtid >> 4;
    int l = threadIdx.x & 15;
    if (idx >= 2 * BATCH_C) return;
    int node = (idx < BATCH_C) ? users[idx] : (NUM_USERS + items[idx - BATCH_C]);
    ((float4*)(acc_sel + (size_t)idx * DIM))[l] =
        ((const float4*)(X + (size_t)node * DIM))[l];
}

__global__ __launch_bounds__(256) void add_sel_kernel(const int* __restrict__ users,
                                                      const int* __restrict__ items,
                                                      const float* __restrict__ h,
                                                      float* __restrict__ acc_sel) {
    int gtid = blockIdx.x * blockDim.x + threadIdx.x;
    int idx = gtid >> 4;
    int l = threadIdx.x & 15;
    if (idx >= 2 * BATCH_C) return;
    int node = (idx < BATCH_C) ? users[idx] : (NUM_USERS + items[idx - BATCH_C]);
    float4 a = ((float4*)(acc_sel + (size_t)idx * DIM))[l];
    float4 b = ((const float4*)(h + (size_t)node * DIM))[l];
    a.x += b.x; a.y += b.y; a.z += b.z; a.w += b.w;
    ((float4*)(acc_sel + (size_t)idx * DIM))[l] = a;
}

__global__ __launch_bounds__(256) void dot_kernel(const float* __restrict__ acc_sel,
                                                  float* __restrict__ out) {
    int gtid = blockIdx.x * blockDim.x + threadIdx.x;
    int b = gtid >> 6;
    int lane = threadIdx.x & 63;
    if (b >= BATCH_C) return;
    float u = acc_sel[(size_t)b * DIM + lane];
    float v = acc_sel[(size_t)(BATCH_C + b) * DIM + lane];
    float p = u * v;
    for (int off = 32; off > 0; off >>= 1) p += __shfl_xor(p, off);
    if (lane == 0) out[b] = p * 0.0625f;  // (1/4)^2 for the two light_out rows
}

// ======== launch ========

extern "C" void kernel_launch(void* const* d_in, const int* in_sizes, int n_in,
                              void* d_out, int out_size, void* d_ws, size_t ws_size,
                              hipStream_t stream) {
    const int*   users = (const int*)d_in[0];
    const int*   items = (const int*)d_in[1];
    const float* uemb  = (const float*)d_in[2];
    const float* iemb  = (const float*)d_in[3];
    const int*   esrc  = (const int*)d_in[4];
    const int*   edst  = (const int*)d_in[5];
    const float* eval  = (const float*)d_in[6];
    float*       out   = (float*)d_out;

    char* ws = (char*)d_ws;
    int2*  packed    = (int2*)(ws + 0);              // 80,000,000 (exact CSR)
    int2*  binBuf    = (int2*)(ws + 80000000);       // 80,000,000 (dead after finD)
    float* X         = (float*)(ws + 80000000);      // 38,400,000 (overlays binBuf)
    float* hA        = (float*)(ws + 118400000);     // 38,400,000 (overlays binBuf)
    int*   H         = (int*)(ws + 160000000);       //  9,601,024 (NBLK x NBINS)
    int*   bin_cnt   = (int*)(ws + 169601024);       //      4,688
    int*   bin_start = (int*)(ws + 169605712);       //      4,692
    int*   row_ptr   = (int*)(ws + 169610404);       //    600,004
    float* acc_sel   = (float*)(ws + 170210416);     //  2,097,152

    // 1) atomic-free CSR build
    histA_kernel<<<NBLK, 256, 0, stream>>>(edst, H);
    scanB1_kernel<<<NBINS, 256, 0, stream>>>(H, bin_cnt);
    scanB2_kernel<<<1, 256, 0, stream>>>(bin_cnt, bin_start, row_ptr);
    partC_kernel<<<NBLK, 256, 0, stream>>>(esrc, edst, eval, H, bin_start, binBuf);
    finD_kernel<<<NBINS, 256, 0, stream>>>(binBuf, bin_start, packed, row_ptr);

    // 2) X = concat (overlays binBuf AFTER finD); selected-row init
    concat_kernel<<<2048, 256, 0, stream>>>(uemb, iemb, (float4*)X);
    init_sel_kernel<<<(2 * BATCH_C * 16 + 255) / 256, 256, 0, stream>>>(users, items, X, acc_sel);

    // 3) layers 1,2 full; layer 3 restricted to batch
    const int spmm_blocks = N_NODES / 4;
    spmm_kernel<<<spmm_blocks, 256, 0, stream>>>(packed, row_ptr, X, hA);
    add_sel_kernel<<<(2 * BATCH_C * 16 + 255) / 256, 256, 0, stream>>>(users, items, hA, acc_sel);
    spmm_kernel<<<spmm_blocks, 256, 0, stream>>>(packed, row_ptr, hA, X);
    add_sel_kernel<<<(2 * BATCH_C * 16 + 255) / 256, 256, 0, stream>>>(users, items, X, acc_sel);
    spmm_sel_kernel<<<(2 * BATCH_C) / 4, 256, 0, stream>>>(packed, row_ptr, users, items, X, acc_sel);

    // 4) final dot products
    dot_kernel<<<BATCH_C / 4, 256, 0, stream>>>(acc_sel, out);
}

// Round 14
// 1106.253 us; speedup vs baseline: 1.0518x; 1.0518x over previous
//
#include <hip/hip_runtime.h>

#define NUM_USERS 100000
#define NUM_ITEMS 50000
#define N_NODES   150000   // NUM_USERS + NUM_ITEMS
#define DIM       64
#define NNZ_C     10000000
#define BATCH_C   4096
#define NBINS     1172     // ceil(150000/128); bin = dst >> 7 (128 nodes/bin)
#define NBLK      4096
#define CHUNK     2444     // 4*611; 4096*2444 = 10,010,624 >= NNZ; beg 16B-aligned

// ======== Phase A: per-block histogram over bins (LDS atomics only) ========

__global__ __launch_bounds__(256) void histA_kernel(const int* __restrict__ dst,
                                                    int* __restrict__ H) {
    __shared__ int hist[NBINS];
    int bid = blockIdx.x, t = threadIdx.x;
    for (int i = t; i < NBINS; i += 256) hist[i] = 0;
    __syncthreads();
    int beg = bid * CHUNK;
    int end = beg + CHUNK; if (end > NNZ_C) end = NNZ_C;
    for (int i = beg + t * 4; i < end; i += 1024) {   // beg,end always /4
        int4 d = *(const int4*)(dst + i);
        atomicAdd(&hist[d.x >> 7], 1);
        atomicAdd(&hist[d.y >> 7], 1);
        atomicAdd(&hist[d.z >> 7], 1);
        atomicAdd(&hist[d.w >> 7], 1);
    }
    __syncthreads();
    for (int i = t; i < NBINS; i += 256) H[bid * NBINS + i] = hist[i];
}

// ======== Phase B1: per-bin exclusive scan over blocks (H -> O_rel) ========

__global__ __launch_bounds__(256) void scanB1_kernel(int* __restrict__ H,
                                                     int* __restrict__ bin_cnt) {
    __shared__ int sh[256];
    int b = blockIdx.x;
    int t = threadIdx.x;          // covers blocks [t*16, t*16+16)
    int v[16]; int s = 0;
    #pragma unroll
    for (int j = 0; j < 16; ++j) { v[j] = H[(t * 16 + j) * NBINS + b]; s += v[j]; }
    sh[t] = s;
    __syncthreads();
    for (int off = 1; off < 256; off <<= 1) {
        int x = (t >= off) ? sh[t - off] : 0;
        __syncthreads();
        sh[t] += x;
        __syncthreads();
    }
    int run = sh[t] - s;
    if (t == 255) bin_cnt[b] = sh[255];
    #pragma unroll
    for (int j = 0; j < 16; ++j) { H[(t * 16 + j) * NBINS + b] = run; run += v[j]; }
}

// ======== Phase B2: exclusive scan of bin counts -> bin_start ========

__global__ void scanB2_kernel(const int* __restrict__ bin_cnt,
                              int* __restrict__ bin_start,
                              int* __restrict__ row_ptr) {
    __shared__ int sh[256];
    int t = threadIdx.x;
    int v[5]; int s = 0;
    #pragma unroll
    for (int j = 0; j < 5; ++j) {
        int idx = t * 5 + j;
        v[j] = (idx < NBINS) ? bin_cnt[idx] : 0;
        s += v[j];
    }
    sh[t] = s;
    __syncthreads();
    for (int off = 1; off < 256; off <<= 1) {
        int x = (t >= off) ? sh[t - off] : 0;
        __syncthreads();
        sh[t] += x;
        __syncthreads();
    }
    int run = sh[t] - s;
    #pragma unroll
    for (int j = 0; j < 5; ++j) {
        int idx = t * 5 + j;
        if (idx < NBINS) bin_start[idx] = run;
        run += v[j];
    }
    if (t == 0) { bin_start[NBINS] = NNZ_C; row_ptr[N_NODES] = NNZ_C; }
}

// ======== Phase C: LDS counting-sort by bin, stream to bin-contiguous buf ===
// CHUNK 2444 -> LDS ~34.8KB -> 4 blocks/CU (was 2 at 59KB). Vectorized loads.

__global__ __launch_bounds__(256) void partC_kernel(const int* __restrict__ src,
                                                    const int* __restrict__ dst,
                                                    const float* __restrict__ val,
                                                    const int* __restrict__ H,   // O_rel
                                                    const int* __restrict__ bin_start,
                                                    int2* __restrict__ binBuf) {
    __shared__ int2  edg[CHUNK];     // 19,552 B
    __shared__ short ebin[CHUNK];    //  4,888 B
    __shared__ int   hist[NBINS];    //  4,688 B (later: cursor)
    __shared__ int   lscan[NBINS];   //  4,688 B
    __shared__ int   sh2[256];       //  1,024 B   (total ~34.8 KB)
    int bid = blockIdx.x, t = threadIdx.x;
    int beg = bid * CHUNK;
    int end = beg + CHUNK; if (end > NNZ_C) end = NNZ_C;
    int cnt = end - beg;

    for (int i = t; i < NBINS; i += 256) hist[i] = 0;
    __syncthreads();
    for (int i = beg + t * 4; i < end; i += 1024) {
        int4 d = *(const int4*)(dst + i);
        atomicAdd(&hist[d.x >> 7], 1);
        atomicAdd(&hist[d.y >> 7], 1);
        atomicAdd(&hist[d.z >> 7], 1);
        atomicAdd(&hist[d.w >> 7], 1);
    }
    __syncthreads();

    int v[5]; int s = 0;
    #pragma unroll
    for (int j = 0; j < 5; ++j) {
        int idx = t * 5 + j;
        v[j] = (idx < NBINS) ? hist[idx] : 0;
        s += v[j];
    }
    sh2[t] = s;
    __syncthreads();
    for (int off = 1; off < 256; off <<= 1) {
        int x = (t >= off) ? sh2[t - off] : 0;
        __syncthreads();
        sh2[t] += x;
        __syncthreads();
    }
    int run = sh2[t] - s;
    #pragma unroll
    for (int j = 0; j < 5; ++j) {
        int idx = t * 5 + j;
        if (idx < NBINS) lscan[idx] = run;
        run += v[j];
    }
    __syncthreads();
    for (int i = t; i < NBINS; i += 256) hist[i] = 0;   // reset as cursor
    __syncthreads();

    for (int i = beg + t * 4; i < end; i += 1024) {
        int4   d4 = *(const int4*)(dst + i);
        int4   s4 = *(const int4*)(src + i);
        float4 v4 = *(const float4*)(val + i);
        {
            int b = d4.x >> 7, ld = d4.x & 127;
            int pos = lscan[b] + atomicAdd(&hist[b], 1);
            edg[pos] = make_int2(s4.x | (ld << 18), __float_as_int(v4.x));
            ebin[pos] = (short)b;
        }
        {
            int b = d4.y >> 7, ld = d4.y & 127;
            int pos = lscan[b] + atomicAdd(&hist[b], 1);
            edg[pos] = make_int2(s4.y | (ld << 18), __float_as_int(v4.y));
            ebin[pos] = (short)b;
        }
        {
            int b = d4.z >> 7, ld = d4.z & 127;
            int pos = lscan[b] + atomicAdd(&hist[b], 1);
            edg[pos] = make_int2(s4.z | (ld << 18), __float_as_int(v4.z));
            ebin[pos] = (short)b;
        }
        {
            int b = d4.w >> 7, ld = d4.w & 127;
            int pos = lscan[b] + atomicAdd(&hist[b], 1);
            edg[pos] = make_int2(s4.w | (ld << 18), __float_as_int(v4.w));
            ebin[pos] = (short)b;
        }
    }
    __syncthreads();

    for (int i = t; i < cnt; i += 256) {
        int b = ebin[i];
        int addr = bin_start[b] + H[bid * NBINS + b] + (i - lscan[b]);
        binBuf[addr] = edg[i];
    }
}

// ======== Phase D: per-bin CSR finalize (one workgroup per bin) ========

__global__ __launch_bounds__(256) void finD_kernel(const int2* __restrict__ binBuf,
                                                   const int* __restrict__ bin_start,
                                                   int2* __restrict__ packed,
                                                   int* __restrict__ row_ptr) {
    __shared__ int hist[128], lscan[128], cur[128];
    int b = blockIdx.x, t = threadIdx.x;
    int beg = bin_start[b], end = bin_start[b + 1];
    if (t < 128) hist[t] = 0;
    __syncthreads();
    for (int i = beg + t; i < end; i += 256)
        atomicAdd(&hist[(binBuf[i].x >> 18) & 127], 1);
    __syncthreads();
    int sv = (t < 128) ? hist[t] : 0;
    if (t < 128) lscan[t] = sv;
    __syncthreads();
    for (int off = 1; off < 128; off <<= 1) {
        int x = 0;
        if (t < 128 && t >= off) x = lscan[t - off];
        __syncthreads();
        if (t < 128) lscan[t] += x;
        __syncthreads();
    }
    if (t < 128) {
        lscan[t] -= sv;
        cur[t] = 0;
        int node = b * 128 + t;
        if (node < N_NODES) row_ptr[node] = beg + lscan[t];
    }
    __syncthreads();
    for (int i = beg + t; i < end; i += 256) {
        int2 e = binBuf[i];
        int ld = (e.x >> 18) & 127;
        int slot = beg + lscan[ld] + atomicAdd(&cur[ld], 1);
        packed[slot] = make_int2(e.x & 0x3FFFF, e.y);
    }
}

// ======== X = concat(uemb, iemb) ========

__global__ __launch_bounds__(256) void concat_kernel(const float* __restrict__ uemb,
                                                     const float* __restrict__ iemb,
                                                     float4* __restrict__ X4) {
    const int NU4 = NUM_USERS * DIM / 4;
    const int NT4 = N_NODES * DIM / 4;
    int i = blockIdx.x * blockDim.x + threadIdx.x;
    int stride = gridDim.x * blockDim.x;
    const float4* u4 = (const float4*)uemb;
    const float4* i4 = (const float4*)iemb;
    for (; i < NT4; i += stride)
        X4[i] = (i < NU4) ? u4[i] : i4[i - NU4];
}

// ======== SpMM (measured r12 form, 322 us; r13 ILP-staging reverted) ========

__global__ __launch_bounds__(256) void spmm_kernel(const int2* __restrict__ packed,
                                                   const int* __restrict__ row_ptr,
                                                   const float* __restrict__ xin,
                                                   float* __restrict__ xout) {
    int gtid = blockIdx.x * blockDim.x + threadIdx.x;
    int node = gtid >> 6;
    int lane = threadIdx.x & 63;
    if (node >= N_NODES) return;
    int beg = row_ptr[node];
    int end = row_ptr[node + 1];
    int q  = lane >> 4;
    int d4 = lane & 15;
    const float4* xbase = (const float4*)xin + d4;
    float4 acc = make_float4(0.f, 0.f, 0.f, 0.f);

    for (int base = beg; base < end; base += 64) {
        int n = end - base;
        n = n > 64 ? 64 : n;
        int2 p = make_int2(0, 0);
        if (lane < n) p = packed[base + lane];
        if (n == 64) {
            #pragma unroll
            for (int t = 0; t < 16; ++t) {
                int srclane = (4 * t + q) << 2;
                int s  = __builtin_amdgcn_ds_bpermute(srclane, p.x);
                float v = __int_as_float(__builtin_amdgcn_ds_bpermute(srclane, p.y));
                float4 r = xbase[s * 16];
                acc.x = fmaf(v, r.x, acc.x);
                acc.y = fmaf(v, r.y, acc.y);
                acc.z = fmaf(v, r.z, acc.z);
                acc.w = fmaf(v, r.w, acc.w);
            }
        } else {
            int nq = (n + 3) >> 2;
            #pragma unroll 4
            for (int t = 0; t < nq; ++t) {
                int srclane = (4 * t + q) << 2;
                int s  = __builtin_amdgcn_ds_bpermute(srclane, p.x);
                float v = __int_as_float(__builtin_amdgcn_ds_bpermute(srclane, p.y));
                float4 r = xbase[s * 16];
                acc.x = fmaf(v, r.x, acc.x);
                acc.y = fmaf(v, r.y, acc.y);
                acc.z = fmaf(v, r.z, acc.z);
                acc.w = fmaf(v, r.w, acc.w);
            }
        }
    }
    acc.x += __shfl_xor(acc.x, 16);
    acc.y += __shfl_xor(acc.y, 16);
    acc.z += __shfl_xor(acc.z, 16);
    acc.w += __shfl_xor(acc.w, 16);
    acc.x += __shfl_xor(acc.x, 32);
    acc.y += __shfl_xor(acc.y, 32);
    acc.z += __shfl_xor(acc.z, 32);
    acc.w += __shfl_xor(acc.w, 32);
    if (lane < 16)
        ((float4*)(xout + (size_t)node * DIM))[d4] = acc;
}

__global__ __launch_bounds__(256) void spmm_sel_kernel(const int2* __restrict__ packed,
                                                       const int* __restrict__ row_ptr,
                                                       const int* __restrict__ users,
                                                       const int* __restrict__ items,
                                                       const float* __restrict__ h2,
                                                       float* __restrict__ acc_sel) {
    int gtid = blockIdx.x * blockDim.x + threadIdx.x;
    int slot = gtid >> 6;
    int lane = threadIdx.x & 63;
    if (slot >= 2 * BATCH_C) return;
    int node = (slot < BATCH_C) ? users[slot] : (NUM_USERS + items[slot - BATCH_C]);
    int beg = row_ptr[node];
    int end = row_ptr[node + 1];
    int q  = lane >> 4;
    int d4 = lane & 15;
    const float4* xbase = (const float4*)h2 + d4;
    float4 acc = make_float4(0.f, 0.f, 0.f, 0.f);

    for (int base = beg; base < end; base += 64) {
        int n = end - base;
        n = n > 64 ? 64 : n;
        int2 p = make_int2(0, 0);
        if (lane < n) p = packed[base + lane];
        int nq = (n + 3) >> 2;
        #pragma unroll 4
        for (int t = 0; t < nq; ++t) {
            int srclane = (4 * t + q) << 2;
            int s  = __builtin_amdgcn_ds_bpermute(srclane, p.x);
            float v = __int_as_float(__builtin_amdgcn_ds_bpermute(srclane, p.y));
            float4 r = xbase[s * 16];
            acc.x = fmaf(v, r.x, acc.x);
            acc.y = fmaf(v, r.y, acc.y);
            acc.z = fmaf(v, r.z, acc.z);
            acc.w = fmaf(v, r.w, acc.w);
        }
    }
    acc.x += __shfl_xor(acc.x, 16);
    acc.y += __shfl_xor(acc.y, 16);
    acc.z += __shfl_xor(acc.z, 16);
    acc.w += __shfl_xor(acc.w, 16);
    acc.x += __shfl_xor(acc.x, 32);
    acc.y += __shfl_xor(acc.y, 32);
    acc.z += __shfl_xor(acc.z, 32);
    acc.w += __shfl_xor(acc.w, 32);
    if (lane < 16) {
        float4* dst4 = (float4*)(acc_sel + (size_t)slot * DIM) + d4;
        float4 a = *dst4;
        a.x += acc.x; a.y += acc.y; a.z += acc.z; a.w += acc.w;
        *dst4 = a;
    }
}

// ======== selected-row accumulation + dot ========

__global__ __launch_bounds__(256) void init_sel_kernel(const int* __restrict__ users,
                                                       const int* __restrict__ items,
                                                       const float* __restrict__ X,
                                                       float* __restrict__ acc_sel) {
    int gtid = blockIdx.x * blockDim.x + threadIdx.x;
    int idx = gtid >> 4;
    int l = threadIdx.x & 15;
    if (idx >= 2 * BATCH_C) return;
    int node = (idx < BATCH_C) ? users[idx] : (NUM_USERS + items[idx - BATCH_C]);
    ((float4*)(acc_sel + (size_t)idx * DIM))[l] =
        ((const float4*)(X + (size_t)node * DIM))[l];
}

__global__ __launch_bounds__(256) void add_sel_kernel(const int* __restrict__ users,
                                                      const int* __restrict__ items,
                                                      const float* __restrict__ h,
                                                      float* __restrict__ acc_sel) {
    int gtid = blockIdx.x * blockDim.x + threadIdx.x;
    int idx = gtid >> 4;
    int l = threadIdx.x & 15;
    if (idx >= 2 * BATCH_C) return;
    int node = (idx < BATCH_C) ? users[idx] : (NUM_USERS + items[idx - BATCH_C]);
    float4 a = ((float4*)(acc_sel + (size_t)idx * DIM))[l];
    float4 b = ((const float4*)(h + (size_t)node * DIM))[l];
    a.x += b.x; a.y += b.y; a.z += b.z; a.w += b.w;
    ((float4*)(acc_sel + (size_t)idx * DIM))[l] = a;
}

__global__ __launch_bounds__(256) void dot_kernel(const float* __restrict__ acc_sel,
                                                  float* __restrict__ out) {
    int gtid = blockIdx.x * blockDim.x + threadIdx.x;
    int b = gtid >> 6;
    int lane = threadIdx.x & 63;
    if (b >= BATCH_C) return;
    float u = acc_sel[(size_t)b * DIM + lane];
    float v = acc_sel[(size_t)(BATCH_C + b) * DIM + lane];
    float p = u * v;
    for (int off = 32; off > 0; off >>= 1) p += __shfl_xor(p, off);
    if (lane == 0) out[b] = p * 0.0625f;  // (1/4)^2 for the two light_out rows
}

// ======== launch ========

extern "C" void kernel_launch(void* const* d_in, const int* in_sizes, int n_in,
                              void* d_out, int out_size, void* d_ws, size_t ws_size,
                              hipStream_t stream) {
    const int*   users = (const int*)d_in[0];
    const int*   items = (const int*)d_in[1];
    const float* uemb  = (const float*)d_in[2];
    const float* iemb  = (const float*)d_in[3];
    const int*   esrc  = (const int*)d_in[4];
    const int*   edst  = (const int*)d_in[5];
    const float* eval  = (const float*)d_in[6];
    float*       out   = (float*)d_out;

    char* ws = (char*)d_ws;
    int2*  packed    = (int2*)(ws + 0);              // 80,000,000 (exact CSR)
    int2*  binBuf    = (int2*)(ws + 80000000);       // 80,000,000 (dead after finD)
    float* X         = (float*)(ws + 80000000);      // 38,400,000 (overlays binBuf)
    float* hA        = (float*)(ws + 118400000);     // 38,400,000 (overlays binBuf)
    int*   H         = (int*)(ws + 160000000);       // 19,202,048 (NBLK x NBINS)
    int*   bin_cnt   = (int*)(ws + 179202048);       //      4,688
    int*   bin_start = (int*)(ws + 179206736);       //      4,692
    int*   row_ptr   = (int*)(ws + 179211428);       //    600,004
    float* acc_sel   = (float*)(ws + 179811440);     //  2,097,152 (16B aligned)
    // ends ~181.9 MB < 233 MB (established round 11)

    // 1) atomic-free CSR build
    histA_kernel<<<NBLK, 256, 0, stream>>>(edst, H);
    scanB1_kernel<<<NBINS, 256, 0, stream>>>(H, bin_cnt);
    scanB2_kernel<<<1, 256, 0, stream>>>(bin_cnt, bin_start, row_ptr);
    partC_kernel<<<NBLK, 256, 0, stream>>>(esrc, edst, eval, H, bin_start, binBuf);
    finD_kernel<<<NBINS, 256, 0, stream>>>(binBuf, bin_start, packed, row_ptr);

    // 2) X = concat (overlays binBuf AFTER finD); selected-row init
    concat_kernel<<<2048, 256, 0, stream>>>(uemb, iemb, (float4*)X);
    init_sel_kernel<<<(2 * BATCH_C * 16 + 255) / 256, 256, 0, stream>>>(users, items, X, acc_sel);

    // 3) layers 1,2 full; layer 3 restricted to batch
    const int spmm_blocks = N_NODES / 4;
    spmm_kernel<<<spmm_blocks, 256, 0, stream>>>(packed, row_ptr, X, hA);
    add_sel_kernel<<<(2 * BATCH_C * 16 + 255) / 256, 256, 0, stream>>>(users, items, hA, acc_sel);
    spmm_kernel<<<spmm_blocks, 256, 0, stream>>>(packed, row_ptr, hA, X);
    add_sel_kernel<<<(2 * BATCH_C * 16 + 255) / 256, 256, 0, stream>>>(users, items, X, acc_sel);
    spmm_sel_kernel<<<(2 * BATCH_C) / 4, 256, 0, stream>>>(packed, row_ptr, users, items, X, acc_sel);

    // 4) final dot products
    dot_kernel<<<BATCH_C / 4, 256, 0, stream>>>(acc_sel, out);
}